// Round 9
// baseline (247.352 us; speedup 1.0000x reference)
//
#include <hip/hip_runtime.h>
#include <stdint.h>

#define N_   2048      // boxes per batch
#define NW   64        // u32 words per mask row (N_/32)
#define CLS  4
#define B_   4
#define ORD_STRIDE (N_ + 64)   // sorted order padded for scan staging overshoot

// ---------------- Kernel A: pairwise IoU -> bitmask (ballot form) ----------
__global__ __launch_bounds__(256) void build_mask(
    const float4* __restrict__ boxes, const float* __restrict__ thr_p,
    uint32_t* __restrict__ ov)
{
  __shared__ float4 sb[N_];                 // 32 KiB: all boxes of this batch
  const int b    = blockIdx.x >> 6;         // 64 tiles per batch
  const int tile = blockIdx.x & 63;         // 32 rows per tile
  const float thr = thr_p[0];
  for (int i = threadIdx.x; i < N_; i += 256) sb[i] = boxes[b * N_ + i];
  __syncthreads();
  const int wv = threadIdx.x >> 6;          // wave 0..3
  const int ln = threadIdx.x & 63;
  const int r0 = tile * 32 + wv * 8;        // 8 rows per wave
  float4 bi[8]; float areai[8];
  #pragma unroll
  for (int rr = 0; rr < 8; ++rr) {
    bi[rr] = sb[r0 + rr];
    areai[rr] = (bi[rr].z - bi[rr].x) * (bi[rr].w - bi[rr].y);
  }
  uint32_t myw[8] = {0, 0, 0, 0, 0, 0, 0, 0};
  for (int g = 0; g < 32; ++g) {            // 64 boxes per group
    const float4 bj = sb[g * 64 + ln];
    const float areaj = (bj.z - bj.x) * (bj.w - bj.y);
    const bool sel = ((ln >> 1) == g);
    const bool hi  = (ln & 1);
    #pragma unroll
    for (int rr = 0; rr < 8; ++rr) {        // 8 independent IoU chains per load
      const float xx1 = fmaxf(bi[rr].x, bj.x);
      const float yy1 = fmaxf(bi[rr].y, bj.y);
      const float xx2 = fminf(bi[rr].z, bj.z);
      const float yy2 = fminf(bi[rr].w, bj.w);
      const float iw = fmaxf(xx2 - xx1, 0.0f);
      const float ih = fmaxf(yy2 - yy1, 0.0f);
      const float inter = iw * ih;
      const float uni = fmaxf(areai[rr] + areaj - inter, 1e-6f);
      const unsigned long long bal = __ballot(inter / uni > thr); // ref op order
      const uint32_t w = hi ? (uint32_t)(bal >> 32) : (uint32_t)bal;
      if (sel) myw[rr] = w;
    }
  }
  #pragma unroll
  for (int rr = 0; rr < 8; ++rr)
    ov[((size_t)(b * N_ + r0 + rr)) * NW + ln] = myw[rr]; // 256B coalesced
}

// ---------------- Kernel B: fused sort + asm branch-scan + leader-extract ---
// Scan chain per candidate is now 3 ops: v_and -> v_cmp_ne vcc -> s_cbranch;
// the v_or only executes for leaders. 3 prep-VALU instrs sit between v_cmp
// and the branch to satisfy the VALU->VCC wait-state requirement. Loads stay
// unconditional (after the skip label) so vmcnt counts are exact.
// Reg map: v32 lane, v33 l*4, v34 lead, v36/v37/v44 temps, v38 addr,
// v39 LDS ptr, v45 const1; bits A/B/C v48-63/64-79/80-95;
// rows A/B/C v96-111/112-127/128-143; stage S0/S1/S2 v144-159/160-175/176-191.

#define C_(r,b,s) \
  "v_and_b32 v36, v" #r ", v34\n\t"              \
  "v_lshlrev_b32 v38, 8, v" #s "\n\t"            \
  "v_cmp_ne_u32 vcc, 0, v36\n\t"                 \
  "v_add_u32 v38, v38, v33\n\t"                  \
  "v_bfe_u32 v44, v" #s ", 5, 6\n\t"             \
  "v_cmp_eq_u32 s[48:49], v44, v32\n\t"          \
  "s_cbranch_vccnz 1f\n\t"                       \
  "v_or_b32 v34, v34, v" #b "\n\t"               \
  "1:\n\t"                                       \
  "global_load_dword v" #r ", v38, %[B]\n\t"     \
  "v_cndmask_b32 v37, 0, v45, s[48:49]\n\t"      \
  "v_lshlrev_b32 v" #b ", v" #s ", v37\n\t"

#define P_(r,b,s) \
  "v_lshlrev_b32 v38, 8, v" #s "\n\t"            \
  "v_add_u32 v38, v38, v33\n\t"                  \
  "global_load_dword v" #r ", v38, %[B]\n\t"     \
  "v_bfe_u32 v44, v" #s ", 5, 6\n\t"             \
  "v_cmp_eq_u32 s[48:49], v44, v32\n\t"          \
  "v_cndmask_b32 v37, 0, v45, s[48:49]\n\t"      \
  "v_lshlrev_b32 v" #b ", v" #s ", v37\n\t"

#define E_(r,b) \
  "v_and_b32 v36, v" #r ", v34\n\t"              \
  "v_cmp_ne_u32 vcc, 0, v36\n\t"                 \
  "s_nop 4\n\t"                                  \
  "s_cbranch_vccnz 1f\n\t"                       \
  "v_or_b32 v34, v34, v" #b "\n\t"               \
  "1:\n\t"

#define DSR0 \
  "ds_read_b128 v[144:147], v39\n\t"             \
  "ds_read_b128 v[148:151], v39 offset:16\n\t"   \
  "ds_read_b128 v[152:155], v39 offset:32\n\t"   \
  "ds_read_b128 v[156:159], v39 offset:48\n\t"   \
  "v_add_u32 v39, 64, v39\n\t"
#define DSR1 \
  "ds_read_b128 v[160:163], v39\n\t"             \
  "ds_read_b128 v[164:167], v39 offset:16\n\t"   \
  "ds_read_b128 v[168:171], v39 offset:32\n\t"   \
  "ds_read_b128 v[172:175], v39 offset:48\n\t"   \
  "v_add_u32 v39, 64, v39\n\t"
#define DSR2 \
  "ds_read_b128 v[176:179], v39\n\t"             \
  "ds_read_b128 v[180:183], v39 offset:16\n\t"   \
  "ds_read_b128 v[184:187], v39 offset:32\n\t"   \
  "ds_read_b128 v[188:191], v39 offset:48\n\t"   \
  "v_add_u32 v39, 64, v39\n\t"

#define CL_A \
  C_(96,48,144)  C_(97,49,145)  C_(98,50,146)  C_(99,51,147)  \
  C_(100,52,148) C_(101,53,149) C_(102,54,150) C_(103,55,151) \
  C_(104,56,152) C_(105,57,153) C_(106,58,154) C_(107,59,155) \
  C_(108,60,156) C_(109,61,157) C_(110,62,158) C_(111,63,159)
#define CL_B \
  C_(112,64,160) C_(113,65,161) C_(114,66,162) C_(115,67,163) \
  C_(116,68,164) C_(117,69,165) C_(118,70,166) C_(119,71,167) \
  C_(120,72,168) C_(121,73,169) C_(122,74,170) C_(123,75,171) \
  C_(124,76,172) C_(125,77,173) C_(126,78,174) C_(127,79,175)
#define CL_C \
  C_(128,80,176) C_(129,81,177) C_(130,82,178) C_(131,83,179) \
  C_(132,84,180) C_(133,85,181) C_(134,86,182) C_(135,87,183) \
  C_(136,88,184) C_(137,89,185) C_(138,90,186) C_(139,91,187) \
  C_(140,92,188) C_(141,93,189) C_(142,94,190) C_(143,95,191)

#define PL_A \
  P_(96,48,144)  P_(97,49,145)  P_(98,50,146)  P_(99,51,147)  \
  P_(100,52,148) P_(101,53,149) P_(102,54,150) P_(103,55,151) \
  P_(104,56,152) P_(105,57,153) P_(106,58,154) P_(107,59,155) \
  P_(108,60,156) P_(109,61,157) P_(110,62,158) P_(111,63,159)
#define PL_B \
  P_(112,64,160) P_(113,65,161) P_(114,66,162) P_(115,67,163) \
  P_(116,68,164) P_(117,69,165) P_(118,70,166) P_(119,71,167) \
  P_(120,72,168) P_(121,73,169) P_(122,74,170) P_(123,75,171) \
  P_(124,76,172) P_(125,77,173) P_(126,78,174) P_(127,79,175)
#define PL_C \
  P_(128,80,176) P_(129,81,177) P_(130,82,178) P_(131,83,179) \
  P_(132,84,180) P_(133,85,181) P_(134,86,182) P_(135,87,183) \
  P_(136,88,184) P_(137,89,185) P_(138,90,186) P_(139,91,187) \
  P_(140,92,188) P_(141,93,189) P_(142,94,190) P_(143,95,191)

#define EL_A \
  E_(96,48)  E_(97,49)  E_(98,50)  E_(99,51)  E_(100,52) E_(101,53) \
  E_(102,54) E_(103,55) E_(104,56) E_(105,57) E_(106,58) E_(107,59) \
  E_(108,60) E_(109,61) E_(110,62) E_(111,63)
#define EL_B \
  E_(112,64) E_(113,65) E_(114,66) E_(115,67) E_(116,68) E_(117,69) \
  E_(118,70) E_(119,71) E_(120,72) E_(121,73) E_(122,74) E_(123,75) \
  E_(124,76) E_(125,77) E_(126,78) E_(127,79)
#define EL_C \
  E_(128,80) E_(129,81) E_(130,82) E_(131,83) E_(132,84) E_(133,85) \
  E_(134,86) E_(135,87) E_(136,88) E_(137,89) E_(138,90) E_(139,91) \
  E_(140,92) E_(141,93) E_(142,94) E_(143,95)

#define PH_A "s_waitcnt vmcnt(32)\n\t" "s_waitcnt lgkmcnt(0)\n\t" DSR1 CL_A
#define PH_B "s_waitcnt vmcnt(32)\n\t" "s_waitcnt lgkmcnt(0)\n\t" DSR2 CL_B
#define PH_C "s_waitcnt vmcnt(32)\n\t" "s_waitcnt lgkmcnt(0)\n\t" DSR0 CL_C

__global__ __launch_bounds__(256, 1) void nms_all(
    const float* __restrict__ scores, const float* __restrict__ sthr_p,
    const uint32_t* __restrict__ ov, int* __restrict__ match)
{
  __shared__ unsigned long long sp[N_];     // 16 KiB: sort keys; later mm[]
  __shared__ __align__(16) int sv[ORD_STRIDE];  // sorted order; later leader list
  __shared__ __align__(16) int rk_s[N_];
  __shared__ uint32_t sup_s[NW];
  __shared__ uint32_t lead_s[NW];
  __shared__ int cnt_s;
  __shared__ int nl_s;

  const int bc = blockIdx.x;                // b*CLS + c
  const int b  = bc / CLS;
  const float sthr = sthr_p[0];
  const float* s = scores + (size_t)bc * N_;

  // ---- phase 1: load + pack + suppressed0 ballot ----
  for (int i = threadIdx.x; i < N_; i += 256) {
    const float v = s[i];
    uint32_t u = __float_as_uint(v);
    u = (u >> 31) ? ~u : (u | 0x80000000u); // monotone float->uint
    sp[i] = ((unsigned long long)u << 32) | (uint32_t)(~(uint32_t)i);
    const unsigned long long bal = __ballot(v <= sthr);
    if ((threadIdx.x & 63) == 0) {          // i is a multiple of 64 here
      sup_s[(i >> 5)]     = (uint32_t)bal;
      sup_s[(i >> 5) + 1] = (uint32_t)(bal >> 32);
    }
  }
  // ---- phase 2: bitonic sort (desc by packed u64 => score desc, idx asc) ---
  for (int size = 2; size <= N_; size <<= 1) {
    for (int stride = size >> 1; stride > 0; stride >>= 1) {
      __syncthreads();
      for (int t = threadIdx.x; t < N_ / 2; t += 256) {
        const int pos = 2 * t - (t & (stride - 1));
        const bool desc = ((t & (size >> 1)) == 0);
        const unsigned long long a = sp[pos], c = sp[pos + stride];
        if (desc != (a > c)) { sp[pos] = c; sp[pos + stride] = a; }
      }
    }
  }
  __syncthreads();
  if (threadIdx.x == 0) {
    int c2 = 0;
    for (int w = 0; w < NW; ++w) c2 += __popc(sup_s[w]);
    cnt_s = N_ - c2;                        // # of score>sthr boxes
    nl_s = 0;
  }
  __syncthreads();
  // ---- phase 3: sv (dup-padded tail) + rank ----
  const int cnt = cnt_s;
  const int last = (cnt > 0) ? (int)~(uint32_t)sp[cnt - 1] : 0;
  for (int i = threadIdx.x; i < N_; i += 256) {
    const int idx = (int)~(uint32_t)sp[i];
    sv[i] = (i < cnt || cnt == 0) ? idx : last;   // idempotent pad
    rk_s[idx] = i;
  }
  for (int i = N_ + threadIdx.x; i < ORD_STRIDE; i += 256) sv[i] = last;
  __syncthreads();

  // ---- phase 4: wave 0 asm scan; waves 1-3 init the min-array (aliases sp) -
  int* mm = (int*)sp;
  const uint32_t* rowb = ov + (size_t)b * N_ * NW;
  if (threadIdx.x < 64) {
    const int l  = threadIdx.x;
    const int l4 = l << 2;
    const uint32_t cb = (uint32_t)(uintptr_t)(&sv[0]);   // LDS byte offset
    uint32_t vlead;
    asm volatile(
      "s_waitcnt vmcnt(0) lgkmcnt(0)\n\t"
      "v_mov_b32 v32, %[LN]\n\t"
      "v_mov_b32 v33, %[L4]\n\t"
      "v_mov_b32 v34, 0\n\t"
      "v_mov_b32 v39, %[CB]\n\t"
      "v_mov_b32 v45, 1\n\t"
      DSR0 "s_waitcnt lgkmcnt(0)\n\t" PL_A
      DSR1 "s_waitcnt lgkmcnt(0)\n\t" PL_B
      DSR2 "s_waitcnt lgkmcnt(0)\n\t" PL_C
      DSR0
      "s_mov_b32 s41, 41\n\t"
      "LSCAN%=:\n\t"
      PH_A PH_B PH_C
      "s_sub_u32 s41, s41, 1\n\t"
      "s_cmp_lg_u32 s41, 0\n\t"
      "s_cbranch_scc1 LSCAN%=\n\t"
      PH_A PH_B                             // phases 123, 124 (last issuing)
      "s_waitcnt vmcnt(32)\n\t" EL_C        // phase 125
      "s_waitcnt vmcnt(16)\n\t" EL_A        // phase 126
      "s_waitcnt vmcnt(0)\n\t"  EL_B        // phase 127
      "v_mov_b32 %[LD], v34\n\t"
      : [LD] "=v"(vlead)
      : [LN] "v"(l), [L4] "v"(l4), [CB] "v"(cb), [B] "s"(rowb)
      : "memory", "scc", "s40", "s41", "s46", "s47", "s48", "s49",
        "v32","v33","v34","v35","v36","v37","v38","v39","v44","v45",
        "v48","v49","v50","v51","v52","v53","v54","v55",
        "v56","v57","v58","v59","v60","v61","v62","v63","v64","v65","v66","v67",
        "v68","v69","v70","v71","v72","v73","v74","v75","v76","v77","v78","v79",
        "v80","v81","v82","v83","v84","v85","v86","v87","v88","v89","v90","v91",
        "v92","v93","v94","v95","v96","v97","v98","v99","v100","v101","v102","v103",
        "v104","v105","v106","v107","v108","v109","v110","v111","v112","v113","v114","v115",
        "v116","v117","v118","v119","v120","v121","v122","v123","v124","v125","v126","v127",
        "v128","v129","v130","v131","v132","v133","v134","v135","v136","v137","v138","v139",
        "v140","v141","v142","v143","v144","v145","v146","v147","v148","v149","v150","v151",
        "v152","v153","v154","v155","v156","v157","v158","v159","v160","v161","v162","v163",
        "v164","v165","v166","v167","v168","v169","v170","v171","v172","v173","v174","v175",
        "v176","v177","v178","v179","v180","v181","v182","v183","v184","v185","v186","v187",
        "v188","v189","v190","v191");
    lead_s[l] = vlead;
  } else {
    for (int i = threadIdx.x - 64; i < N_; i += 192) mm[i] = 0x7FFFFFFF;
  }
  __syncthreads();

  // ---- phase 5: compact leader list (order irrelevant; min is commutative) -
  int* llist = sv;                          // sv is dead post-scan
  for (int q = 0; q < 8; ++q) {
    const int n = threadIdx.x * 8 + q;
    if ((lead_s[n >> 5] >> (n & 31)) & 1u) {
      const int p = atomicAdd(&nl_s, 1);
      llist[p] = n;
    }
  }
  __syncthreads();

  // ---- phase 6: leader-centric scatter-min (4-deep load pipelining) --------
  const int L = nl_s;
  const int wv = threadIdx.x >> 6;
  const int l  = threadIdx.x & 63;
  for (int i0 = wv; i0 < L; i0 += 16) {     // wave-strided, 4 leaders per iter
    const int i1 = i0 + 4, i2 = i0 + 8, i3 = i0 + 12;
    const int la = llist[i0];
    const int lb = (i1 < L) ? llist[i1] : la;
    const int lc = (i2 < L) ? llist[i2] : la;
    const int ld = (i3 < L) ? llist[i3] : la;
    const uint32_t ra = rowb[(size_t)la * NW + l];
    const uint32_t rb = (i1 < L) ? rowb[(size_t)lb * NW + l] : 0u;
    const uint32_t rc = (i2 < L) ? rowb[(size_t)lc * NW + l] : 0u;
    const uint32_t rd = (i3 < L) ? rowb[(size_t)ld * NW + l] : 0u;
    {
      const int pk = (rk_s[la] << 11) | la;
      uint32_t bits = ra;
      while (bits) { const int kk = __ffs(bits) - 1; bits &= bits - 1;
        atomicMin(&mm[(l << 5) + kk], pk); }
    }
    {
      const int pk = (rk_s[lb] << 11) | lb;
      uint32_t bits = rb;
      while (bits) { const int kk = __ffs(bits) - 1; bits &= bits - 1;
        atomicMin(&mm[(l << 5) + kk], pk); }
    }
    {
      const int pk = (rk_s[lc] << 11) | lc;
      uint32_t bits = rc;
      while (bits) { const int kk = __ffs(bits) - 1; bits &= bits - 1;
        atomicMin(&mm[(l << 5) + kk], pk); }
    }
    {
      const int pk = (rk_s[ld] << 11) | ld;
      uint32_t bits = rd;
      while (bits) { const int kk = __ffs(bits) - 1; bits &= bits - 1;
        atomicMin(&mm[(l << 5) + kk], pk); }
    }
  }
  __syncthreads();

  // ---- phase 7: final write (coalesced) ----
  for (int q = 0; q < 8; ++q) {
    const int n = (q << 8) + threadIdx.x;
    const bool below = (sup_s[n >> 5] >> (n & 31)) & 1u;
    const int v = mm[n];
    match[(size_t)bc * N_ + n] = (below || v == 0x7FFFFFFF) ? -1 : (v & 2047);
  }
}

extern "C" void kernel_launch(void* const* d_in, const int* in_sizes, int n_in,
                              void* d_out, int out_size, void* d_ws, size_t ws_size,
                              hipStream_t stream)
{
  const float4* boxes  = (const float4*)d_in[0];   // [B,N,4] f32
  const float*  scores = (const float*)d_in[1];    // [B,C,N] f32
  const float*  iouthr = (const float*)d_in[2];    // [1]
  const float*  scthr  = (const float*)d_in[3];    // [1]
  int* match = (int*)d_out;                        // [B,C,N] int32

  uint32_t* ov = (uint32_t*)d_ws;                  // 2 MiB mask

  build_mask<<<dim3(256),      dim3(256), 0, stream>>>(boxes, iouthr, ov);
  nms_all   <<<dim3(B_ * CLS), dim3(256), 0, stream>>>(scores, scthr, ov, match);
}

// Round 10
// 189.942 us; speedup vs baseline: 1.3022x; 1.3022x over previous
//
#include <hip/hip_runtime.h>
#include <stdint.h>

#define N_   2048      // boxes per batch
#define NW   64        // u32 words per mask row (N_/32)
#define CLS  4
#define B_   4
#define ORD_STRIDE (N_ + 64)   // sorted order padded for scan staging overshoot

// ============================ Kernel 1 ======================================
// blocks 0..63  : mask role — pairwise IoU -> bitmask (ballot form), 16 waves
// blocks 64..79 : sort role — per-(b,c) packed-u64 bitonic argsort, 1 CE/thread
// The two roles are independent and run on disjoint CUs -> wall = max, not sum.
__global__ __launch_bounds__(1024) void mask_or_sort(
    const float4* __restrict__ boxes, const float* __restrict__ thr_p,
    const float* __restrict__ scores, const float* __restrict__ sthr_p,
    uint32_t* __restrict__ ov, int* __restrict__ order,
    int* __restrict__ rk, uint32_t* __restrict__ sup0ws)
{
  __shared__ __align__(16) unsigned char lds_raw[32768];
  __shared__ uint32_t sup_l[NW];
  __shared__ int cnt_s;

  if (blockIdx.x < 64) {
    // ---------------- mask role ----------------
    float4* sb = (float4*)lds_raw;          // 32 KiB: all boxes of this batch
    const int b    = blockIdx.x >> 4;       // 16 blocks per batch
    const int tile = blockIdx.x & 15;       // 128 rows per block
    const float thr = thr_p[0];
    for (int i = threadIdx.x; i < N_; i += 1024) sb[i] = boxes[b * N_ + i];
    __syncthreads();
    const int wv = threadIdx.x >> 6;        // wave 0..15
    const int ln = threadIdx.x & 63;
    const int r0 = tile * 128 + wv * 8;     // 8 rows per wave
    float4 bi[8]; float areai[8];
    #pragma unroll
    for (int rr = 0; rr < 8; ++rr) {
      bi[rr] = sb[r0 + rr];
      areai[rr] = (bi[rr].z - bi[rr].x) * (bi[rr].w - bi[rr].y);
    }
    uint32_t myw[8] = {0, 0, 0, 0, 0, 0, 0, 0};
    for (int g = 0; g < 32; ++g) {          // 64 boxes per group
      const float4 bj = sb[g * 64 + ln];
      const float areaj = (bj.z - bj.x) * (bj.w - bj.y);
      const bool sel = ((ln >> 1) == g);
      const bool hi  = (ln & 1);
      #pragma unroll
      for (int rr = 0; rr < 8; ++rr) {      // 8 independent IoU chains per load
        const float xx1 = fmaxf(bi[rr].x, bj.x);
        const float yy1 = fmaxf(bi[rr].y, bj.y);
        const float xx2 = fminf(bi[rr].z, bj.z);
        const float yy2 = fminf(bi[rr].w, bj.w);
        const float iw = fmaxf(xx2 - xx1, 0.0f);
        const float ih = fmaxf(yy2 - yy1, 0.0f);
        const float inter = iw * ih;
        const float uni = fmaxf(areai[rr] + areaj - inter, 1e-6f);
        const unsigned long long bal = __ballot(inter / uni > thr); // ref op order
        const uint32_t w = hi ? (uint32_t)(bal >> 32) : (uint32_t)bal;
        if (sel) myw[rr] = w;
      }
    }
    #pragma unroll
    for (int rr = 0; rr < 8; ++rr)
      ov[((size_t)(b * N_ + r0 + rr)) * NW + ln] = myw[rr]; // 256B coalesced
  } else {
    // ---------------- sort role ----------------
    unsigned long long* sp = (unsigned long long*)lds_raw;  // 16 KiB
    const int bc = blockIdx.x - 64;         // b*CLS + c
    const float sthr = sthr_p[0];
    const float* s = scores + (size_t)bc * N_;
    for (int i = threadIdx.x; i < N_; i += 1024) {
      const float v = s[i];
      uint32_t u = __float_as_uint(v);
      u = (u >> 31) ? ~u : (u | 0x80000000u);        // monotone float->uint
      sp[i] = ((unsigned long long)u << 32) | (uint32_t)(~(uint32_t)i);
      const unsigned long long bal = __ballot(v <= sthr);
      if ((threadIdx.x & 63) == 0) {        // i is a multiple of 64 here
        sup_l[(i >> 5)]     = (uint32_t)bal;
        sup_l[(i >> 5) + 1] = (uint32_t)(bal >> 32);
      }
    }
    // bitonic: descending by packed u64 => score desc, ties index asc (exact);
    // 1024 threads = N/2 -> exactly one compare-exchange per thread per stage
    const int t = threadIdx.x;
    for (int size = 2; size <= N_; size <<= 1) {
      for (int stride = size >> 1; stride > 0; stride >>= 1) {
        __syncthreads();
        const int pos = 2 * t - (t & (stride - 1));
        const bool desc = ((t & (size >> 1)) == 0);
        const unsigned long long a = sp[pos], c = sp[pos + stride];
        if (desc != (a > c)) { sp[pos] = c; sp[pos + stride] = a; }
      }
    }
    __syncthreads();
    if (threadIdx.x == 0) {
      int c2 = 0;
      for (int w = 0; w < NW; ++w) c2 += __popc(sup_l[w]);
      cnt_s = N_ - c2;                      // # of score>sthr boxes
    }
    __syncthreads();
    const int cnt = cnt_s;
    const int last = (cnt > 0) ? (int)~(uint32_t)sp[cnt - 1] : 0;
    int* ord_o = order + (size_t)bc * ORD_STRIDE;
    int* rk_o  = rk    + (size_t)bc * N_;
    for (int i = threadIdx.x; i < N_; i += 1024) {
      const int idx = (int)~(uint32_t)sp[i];
      ord_o[i] = (i < cnt || cnt == 0) ? idx : last;  // dup-pad tail (idempotent)
      rk_o[idx] = i;
    }
    for (int i = N_ + threadIdx.x; i < ORD_STRIDE; i += 1024) ord_o[i] = last;
    if (threadIdx.x < NW) sup0ws[bc * NW + threadIdx.x] = sup_l[threadIdx.x];
  }
}

// ============================ Kernel 2 ======================================
// asm greedy scan -> leader bitmap, PAIRED candidates: c1,c2 both test against
// the SAME carried lead (2 independent v_ands); c1's effect on c2 is the
// off-chain precomputed o21 = row2 & bit1 (t2' = t2 | (c1-leads ? o21 : 0)).
// Serial chain per pair: cmp,br,or, cmp,br,or. Depth-3 row pipeline unchanged
// (16 loads/phase in same order -> vmcnt(32/16/0) math identical to r8).
// Reg map: v32 lane, v33 l*4, v34 lead, v35/36/37/38/44 temps, v39 LDS ptr,
// v45 const1; bits A/B/C v48-63/64-79/80-95; rows A/B/C v96-111/112-127/
// 128-143; stage S0/S1/S2 v144-159/160-175/176-191.

#define PAIR_(r1,b1,s1,r2,b2,s2) \
  "v_and_b32 v36, v" #r1 ", v34\n\t"             \
  "v_and_b32 v37, v" #r2 ", v34\n\t"             \
  "v_and_b32 v35, v" #r2 ", v" #b1 "\n\t"        \
  "v_cmp_ne_u32 vcc, 0, v36\n\t"                 \
  "v_lshlrev_b32 v38, 8, v" #s1 "\n\t"           \
  "v_add_u32 v38, v38, v33\n\t"                  \
  "v_bfe_u32 v44, v" #s1 ", 5, 6\n\t"            \
  "s_cbranch_vccnz 11f\n\t"                      \
  "v_or_b32 v34, v34, v" #b1 "\n\t"              \
  "v_or_b32 v37, v37, v35\n\t"                   \
  "11:\n\t"                                      \
  "global_load_dword v" #r1 ", v38, %[B]\n\t"    \
  "v_cmp_ne_u32 vcc, 0, v37\n\t"                 \
  "v_cmp_eq_u32 s[48:49], v44, v32\n\t"          \
  "v_lshlrev_b32 v38, 8, v" #s2 "\n\t"           \
  "v_add_u32 v38, v38, v33\n\t"                  \
  "v_cndmask_b32 v35, 0, v45, s[48:49]\n\t"      \
  "s_cbranch_vccnz 12f\n\t"                      \
  "v_or_b32 v34, v34, v" #b2 "\n\t"              \
  "12:\n\t"                                      \
  "global_load_dword v" #r2 ", v38, %[B]\n\t"    \
  "v_lshlrev_b32 v" #b1 ", v" #s1 ", v35\n\t"    \
  "v_bfe_u32 v44, v" #s2 ", 5, 6\n\t"            \
  "v_cmp_eq_u32 s[48:49], v44, v32\n\t"          \
  "v_cndmask_b32 v35, 0, v45, s[48:49]\n\t"      \
  "v_lshlrev_b32 v" #b2 ", v" #s2 ", v35\n\t"

// epilogue pair: test only, no refill
#define EPAIR_(r1,b1,r2,b2) \
  "v_and_b32 v36, v" #r1 ", v34\n\t"             \
  "v_and_b32 v37, v" #r2 ", v34\n\t"             \
  "v_and_b32 v35, v" #r2 ", v" #b1 "\n\t"        \
  "v_cmp_ne_u32 vcc, 0, v36\n\t"                 \
  "s_nop 4\n\t"                                  \
  "s_cbranch_vccnz 13f\n\t"                      \
  "v_or_b32 v34, v34, v" #b1 "\n\t"              \
  "v_or_b32 v37, v37, v35\n\t"                   \
  "13:\n\t"                                      \
  "v_cmp_ne_u32 vcc, 0, v37\n\t"                 \
  "s_nop 4\n\t"                                  \
  "s_cbranch_vccnz 14f\n\t"                      \
  "v_or_b32 v34, v34, v" #b2 "\n\t"              \
  "14:\n\t"

// prologue prep (loads + owner-bit for one candidate, no test) — r8-proven
#define P_(r,b,s) \
  "v_lshlrev_b32 v38, 8, v" #s "\n\t"            \
  "v_add_u32 v38, v38, v33\n\t"                  \
  "global_load_dword v" #r ", v38, %[B]\n\t"     \
  "v_bfe_u32 v44, v" #s ", 5, 6\n\t"             \
  "v_cmp_eq_u32 s[48:49], v44, v32\n\t"          \
  "v_cndmask_b32 v37, 0, v45, s[48:49]\n\t"      \
  "v_lshlrev_b32 v" #b ", v" #s ", v37\n\t"

#define DSR0 \
  "ds_read_b128 v[144:147], v39\n\t"             \
  "ds_read_b128 v[148:151], v39 offset:16\n\t"   \
  "ds_read_b128 v[152:155], v39 offset:32\n\t"   \
  "ds_read_b128 v[156:159], v39 offset:48\n\t"   \
  "v_add_u32 v39, 64, v39\n\t"
#define DSR1 \
  "ds_read_b128 v[160:163], v39\n\t"             \
  "ds_read_b128 v[164:167], v39 offset:16\n\t"   \
  "ds_read_b128 v[168:171], v39 offset:32\n\t"   \
  "ds_read_b128 v[172:175], v39 offset:48\n\t"   \
  "v_add_u32 v39, 64, v39\n\t"
#define DSR2 \
  "ds_read_b128 v[176:179], v39\n\t"             \
  "ds_read_b128 v[180:183], v39 offset:16\n\t"   \
  "ds_read_b128 v[184:187], v39 offset:32\n\t"   \
  "ds_read_b128 v[188:191], v39 offset:48\n\t"   \
  "v_add_u32 v39, 64, v39\n\t"

#define PL_A \
  P_(96,48,144)  P_(97,49,145)  P_(98,50,146)  P_(99,51,147)  \
  P_(100,52,148) P_(101,53,149) P_(102,54,150) P_(103,55,151) \
  P_(104,56,152) P_(105,57,153) P_(106,58,154) P_(107,59,155) \
  P_(108,60,156) P_(109,61,157) P_(110,62,158) P_(111,63,159)
#define PL_B \
  P_(112,64,160) P_(113,65,161) P_(114,66,162) P_(115,67,163) \
  P_(116,68,164) P_(117,69,165) P_(118,70,166) P_(119,71,167) \
  P_(120,72,168) P_(121,73,169) P_(122,74,170) P_(123,75,171) \
  P_(124,76,172) P_(125,77,173) P_(126,78,174) P_(127,79,175)
#define PL_C \
  P_(128,80,176) P_(129,81,177) P_(130,82,178) P_(131,83,179) \
  P_(132,84,180) P_(133,85,181) P_(134,86,182) P_(135,87,183) \
  P_(136,88,184) P_(137,89,185) P_(138,90,186) P_(139,91,187) \
  P_(140,92,188) P_(141,93,189) P_(142,94,190) P_(143,95,191)

#define WAITS "s_waitcnt vmcnt(32)\n\t" "s_waitcnt lgkmcnt(0)\n\t"

#define PH_A WAITS DSR1 \
  PAIR_(96,48,144, 97,49,145)   PAIR_(98,50,146, 99,51,147)   \
  PAIR_(100,52,148, 101,53,149) PAIR_(102,54,150, 103,55,151) \
  PAIR_(104,56,152, 105,57,153) PAIR_(106,58,154, 107,59,155) \
  PAIR_(108,60,156, 109,61,157) PAIR_(110,62,158, 111,63,159)
#define PH_B WAITS DSR2 \
  PAIR_(112,64,160, 113,65,161) PAIR_(114,66,162, 115,67,163) \
  PAIR_(116,68,164, 117,69,165) PAIR_(118,70,166, 119,71,167) \
  PAIR_(120,72,168, 121,73,169) PAIR_(122,74,170, 123,75,171) \
  PAIR_(124,76,172, 125,77,173) PAIR_(126,78,174, 127,79,175)
#define PH_C WAITS DSR0 \
  PAIR_(128,80,176, 129,81,177) PAIR_(130,82,178, 131,83,179) \
  PAIR_(132,84,180, 133,85,181) PAIR_(134,86,182, 135,87,183) \
  PAIR_(136,88,184, 137,89,185) PAIR_(138,90,186, 139,91,187) \
  PAIR_(140,92,188, 141,93,189) PAIR_(142,94,190, 143,95,191)

#define EL_A \
  EPAIR_(96,48,97,49)   EPAIR_(98,50,99,51)   EPAIR_(100,52,101,53) \
  EPAIR_(102,54,103,55) EPAIR_(104,56,105,57) EPAIR_(106,58,107,59) \
  EPAIR_(108,60,109,61) EPAIR_(110,62,111,63)
#define EL_B \
  EPAIR_(112,64,113,65) EPAIR_(114,66,115,67) EPAIR_(116,68,117,69) \
  EPAIR_(118,70,119,71) EPAIR_(120,72,121,73) EPAIR_(122,74,123,75) \
  EPAIR_(124,76,125,77) EPAIR_(126,78,127,79)
#define EL_C \
  EPAIR_(128,80,129,81) EPAIR_(130,82,131,83) EPAIR_(132,84,133,85) \
  EPAIR_(134,86,135,87) EPAIR_(136,88,137,89) EPAIR_(138,90,139,91) \
  EPAIR_(140,92,141,93) EPAIR_(142,94,143,95)

__global__ __launch_bounds__(64, 1) void scan_lead(
    const int* __restrict__ order, const uint32_t* __restrict__ ov,
    uint32_t* __restrict__ leadws)
{
  __shared__ __align__(16) int sv[ORD_STRIDE];
  const int bc = blockIdx.x;                // b*CLS + c
  const int b  = bc / CLS;
  const int l  = threadIdx.x;
  // stage sorted order into LDS (single wave, coalesced int4)
  {
    const int4* src = (const int4*)(order + (size_t)bc * ORD_STRIDE);
    int4* dst = (int4*)sv;
    for (int i = l; i < ORD_STRIDE / 4; i += 64) dst[i] = src[i];
  }
  const int l4 = l << 2;
  const uint32_t cb = (uint32_t)(uintptr_t)(&sv[0]);   // LDS byte offset
  const uint32_t* rowb = ov + (size_t)b * N_ * NW;
  uint32_t vlead;
  asm volatile(
    "s_waitcnt vmcnt(0) lgkmcnt(0)\n\t"
    "v_mov_b32 v32, %[LN]\n\t"
    "v_mov_b32 v33, %[L4]\n\t"
    "v_mov_b32 v34, 0\n\t"
    "v_mov_b32 v39, %[CB]\n\t"
    "v_mov_b32 v45, 1\n\t"
    DSR0 "s_waitcnt lgkmcnt(0)\n\t" PL_A
    DSR1 "s_waitcnt lgkmcnt(0)\n\t" PL_B
    DSR2 "s_waitcnt lgkmcnt(0)\n\t" PL_C
    DSR0
    "s_mov_b32 s41, 41\n\t"
    "LSCAN%=:\n\t"
    PH_A PH_B PH_C
    "s_sub_u32 s41, s41, 1\n\t"
    "s_cmp_lg_u32 s41, 0\n\t"
    "s_cbranch_scc1 LSCAN%=\n\t"
    PH_A PH_B                               // phases 123, 124 (last issuing)
    "s_waitcnt vmcnt(32)\n\t" "s_waitcnt lgkmcnt(0)\n\t" EL_C  // phase 125
    "s_waitcnt vmcnt(16)\n\t" EL_A          // phase 126
    "s_waitcnt vmcnt(0)\n\t"  EL_B          // phase 127
    "v_mov_b32 %[LD], v34\n\t"
    : [LD] "=v"(vlead)
    : [LN] "v"(l), [L4] "v"(l4), [CB] "v"(cb), [B] "s"(rowb)
    : "memory", "scc", "s40", "s41", "s46", "s47", "s48", "s49",
      "v32","v33","v34","v35","v36","v37","v38","v39","v44","v45",
      "v48","v49","v50","v51","v52","v53","v54","v55",
      "v56","v57","v58","v59","v60","v61","v62","v63","v64","v65","v66","v67",
      "v68","v69","v70","v71","v72","v73","v74","v75","v76","v77","v78","v79",
      "v80","v81","v82","v83","v84","v85","v86","v87","v88","v89","v90","v91",
      "v92","v93","v94","v95","v96","v97","v98","v99","v100","v101","v102","v103",
      "v104","v105","v106","v107","v108","v109","v110","v111","v112","v113","v114","v115",
      "v116","v117","v118","v119","v120","v121","v122","v123","v124","v125","v126","v127",
      "v128","v129","v130","v131","v132","v133","v134","v135","v136","v137","v138","v139",
      "v140","v141","v142","v143","v144","v145","v146","v147","v148","v149","v150","v151",
      "v152","v153","v154","v155","v156","v157","v158","v159","v160","v161","v162","v163",
      "v164","v165","v166","v167","v168","v169","v170","v171","v172","v173","v174","v175",
      "v176","v177","v178","v179","v180","v181","v182","v183","v184","v185","v186","v187",
      "v188","v189","v190","v191");
  leadws[bc * NW + l] = vlead;
}

// ---------------- Kernel 3: parallel extraction (wave per box) --------------
// match[n] = original index of the min-rank leader overlapping n (== greedy
// claimant), or -1 if score<=sthr. Coalesced 256B row read per n; per-lane
// bit scan + 6-step shfl_xor min-reduce.
__global__ __launch_bounds__(256) void extract_match(
    const uint32_t* __restrict__ ov, const int* __restrict__ rk,
    const uint32_t* __restrict__ sup0ws, const uint32_t* __restrict__ leadws,
    int* __restrict__ match)
{
  __shared__ __align__(16) int rk_s[N_];
  __shared__ uint32_t lead_s[NW];
  __shared__ uint32_t sup_s[NW];
  const int bc  = blockIdx.x >> 4;          // b*CLS + c
  const int seg = blockIdx.x & 15;          // 128 boxes per block
  const int b   = bc / CLS;
  {
    const int4* src = (const int4*)(rk + (size_t)bc * N_);
    int4* dst = (int4*)rk_s;
    for (int i = threadIdx.x; i < N_ / 4; i += 256) dst[i] = src[i];
    if (threadIdx.x < NW) {
      lead_s[threadIdx.x] = leadws[bc * NW + threadIdx.x];
      sup_s[threadIdx.x]  = sup0ws[bc * NW + threadIdx.x];
    }
  }
  __syncthreads();
  const int wv = threadIdx.x >> 6;
  const int l  = threadIdx.x & 63;
  const uint32_t gl = lead_s[l];
  const uint32_t* Mb = ov + (size_t)b * N_ * NW;
  #pragma unroll 4
  for (int j = 0; j < 32; ++j) {
    const int n = seg * 128 + wv * 32 + j;
    uint32_t bits = Mb[(size_t)n * NW + l] & gl;   // coalesced 256B row
    int minp = 0x7FFFFFFF;
    while (bits) {                          // rare: overlapping leaders
      const int k = __ffs(bits) - 1;
      bits &= bits - 1;
      const int jj = (l << 5) + k;
      const int pk = (rk_s[jj] << 11) | jj;
      minp = (pk < minp) ? pk : minp;
    }
    #pragma unroll
    for (int m = 32; m; m >>= 1) {
      const int o = __shfl_xor(minp, m);
      minp = (o < minp) ? o : minp;
    }
    const bool below = (sup_s[n >> 5] >> (n & 31)) & 1u;
    if (l == 0)
      match[(size_t)bc * N_ + n] =
          (below || minp == 0x7FFFFFFF) ? -1 : (minp & 2047);
  }
}

extern "C" void kernel_launch(void* const* d_in, const int* in_sizes, int n_in,
                              void* d_out, int out_size, void* d_ws, size_t ws_size,
                              hipStream_t stream)
{
  const float4* boxes  = (const float4*)d_in[0];   // [B,N,4] f32
  const float*  scores = (const float*)d_in[1];    // [B,C,N] f32
  const float*  iouthr = (const float*)d_in[2];    // [1]
  const float*  scthr  = (const float*)d_in[3];    // [1]
  int* match = (int*)d_out;                        // [B,C,N] int32

  char* ws = (char*)d_ws;
  uint32_t* ov    = (uint32_t*)ws;                                     // 2 MiB
  int*      order = (int*)(ws + (size_t)B_ * N_ * NW * 4);
  int*      rk    = (int*)((char*)order + (size_t)B_ * CLS * ORD_STRIDE * 4);
  uint32_t* sup0  = (uint32_t*)((char*)rk + (size_t)B_ * CLS * N_ * 4);
  uint32_t* leadw = (uint32_t*)((char*)sup0 + (size_t)B_ * CLS * NW * 4);

  mask_or_sort <<<dim3(64 + B_ * CLS), dim3(1024), 0, stream>>>(
      boxes, iouthr, scores, scthr, ov, order, rk, sup0);
  scan_lead    <<<dim3(B_ * CLS), dim3(64),  0, stream>>>(order, ov, leadw);
  extract_match<<<dim3(256),      dim3(256), 0, stream>>>(ov, rk, sup0, leadw, match);
}